// Round 9
// baseline (88.775 us; speedup 1.0000x reference)
//
#include <hip/hip_runtime.h>
#include <hip/hip_bf16.h>

#define NPTS 4096
#define NROWS 8192   // B*N
#define DIM 128
#define LSTRIDE 264  // ushorts per lane W-block: 2ch*128 + 8 pad = 528 B (16B aligned)

typedef __attribute__((ext_vector_type(8))) short bf16x8;
typedef __attribute__((ext_vector_type(4))) float f32x4;

// ---------- exact f64 packed key: key = f64(d2) with low 12 bits = j ----------
__device__ __forceinline__ double mkkey(float d2, int j) {
    return __longlong_as_double(__double_as_longlong((double)d2) |
                                (unsigned long long)(unsigned)j);
}

// sorted-ascending insert: 7 v_min/max_f64
__device__ __forceinline__ void kins(double& k0, double& k1, double& k2,
                                     double& k3, double s) {
    double c = fmax(k0, s); k0 = fmin(k0, s);
    double t = fmax(k1, c); k1 = fmin(k1, c); c = t;
    t = fmax(k2, c);        k2 = fmin(k2, c); c = t;
    k3 = fmin(k3, c);
}

// merge two sorted-asc 4-lists -> 4 smallest sorted: 12 v_min/max_f64
__device__ __forceinline__ void kmerge(double& a0, double& a1, double& a2,
                                       double& a3, double b0, double b1,
                                       double b2, double b3) {
    double m0 = fmin(a0, b3), m1 = fmin(a1, b2);
    double m2 = fmin(a2, b1), m3 = fmin(a3, b0);
    double t0 = fmin(m0, m2), t2 = fmax(m0, m2);
    double t1 = fmin(m1, m3), t3 = fmax(m1, m3);
    a0 = fmin(t0, t1); a1 = fmax(t0, t1);
    a2 = fmin(t2, t3); a3 = fmax(t2, t3);
}

__device__ __forceinline__ float bf2f(unsigned short u) {
    return __uint_as_float((unsigned)u << 16);
}

// ---------- single fused kernel ----------
// Block = 8 rows (4 waves x 2 rows). Phase A: stage W (bf16, column-pair-major)
// into LDS. Phase B: R4-verified f64-key top-4 scan + butterfly. Phase C:
// aggregate xa = sum w_k * x[j_k] in f32 (exact), xa -> LDS, dot with LDS W.
__global__ __launch_bounds__(256) void gnn_fused(const float* __restrict__ x,
                                                 const float* __restrict__ pos,
                                                 const float* __restrict__ W,
                                                 const float* __restrict__ bias,
                                                 float* __restrict__ out) {
    __shared__ unsigned short sW[64 * LSTRIDE];   // 33 KB
    __shared__ float sxa[4][2][DIM];              // 4 KB

    int lane = threadIdx.x & 63;
    int wave = threadIdx.x >> 6;
    int rowbase = blockIdx.x * 8;              // never straddles batch
    int batch = rowbase >> 12;
    int ibase = rowbase & (NPTS - 1);
    const float* pb = pos + (size_t)batch * NPTS * 3;
    const float* xb = x + (((size_t)batch * NPTS) << 7);

    // ---- phase A: W[k][c] -> sW[(c>>1)*LSTRIDE + (c&1)*128 + k] (bf16) ----
    union { __hip_bfloat16 h; unsigned short u; } cv;
    for (int e = threadIdx.x; e < DIM * DIM; e += 256) {
        int k = e >> 7, c = e & 127;
        cv.h = __float2bfloat16(W[e]);
        sW[(c >> 1) * LSTRIDE + (c & 1) * DIM + k] = cv.u;
    }
    __syncthreads();

    // ---- phase B: scan (2 rows/wave, all 4096 candidates) ----
    int r0 = ibase + wave * 2;
    float q0x = pb[3 * r0 + 0], q0y = pb[3 * r0 + 1], q0z = pb[3 * r0 + 2];
    float q1x = pb[3 * r0 + 3], q1y = pb[3 * r0 + 4], q1z = pb[3 * r0 + 5];

    const double INF = __builtin_inf();
    double a0 = INF, a1 = INF, a2 = INF, a3 = INF;
    double b0 = INF, b1 = INF, b2 = INF, b3 = INF;

#pragma unroll 8
    for (int it = 0; it < NPTS / 64; ++it) {
        int j = it * 64 + lane;
        float px = pb[3 * j + 0];
        float py = pb[3 * j + 1];
        float pz = pb[3 * j + 2];
        float dx = q0x - px, dy = q0y - py, dz = q0z - pz;
        float d2 = fmaf(dx, dx, fmaf(dy, dy, dz * dz));
        kins(a0, a1, a2, a3, mkkey(d2, j));
        dx = q1x - px; dy = q1y - py; dz = q1z - pz;
        d2 = fmaf(dx, dx, fmaf(dy, dy, dz * dz));
        kins(b0, b1, b2, b3, mkkey(d2, j));
    }
#pragma unroll
    for (int off = 1; off < 64; off <<= 1) {
        double p0 = __shfl_xor(a0, off), p1 = __shfl_xor(a1, off);
        double p2 = __shfl_xor(a2, off), p3 = __shfl_xor(a3, off);
        kmerge(a0, a1, a2, a3, p0, p1, p2, p3);
        p0 = __shfl_xor(b0, off); p1 = __shfl_xor(b1, off);
        p2 = __shfl_xor(b2, off); p3 = __shfl_xor(b3, off);
        kmerge(b0, b1, b2, b3, p0, p1, p2, p3);
    }

    // ---- phase C: weights + f32 gather-aggregate -> LDS -> dot with W ----
    int c = lane << 1;
#pragma unroll
    for (int k = 0; k < 2; ++k) {
        double k0 = k ? b0 : a0, k1 = k ? b1 : a1;
        double k2 = k ? b2 : a2, k3 = k ? b3 : a3;
        unsigned i0 = (unsigned)__double_as_longlong(k0) & 0xFFFu;
        unsigned i1 = (unsigned)__double_as_longlong(k1) & 0xFFFu;
        unsigned i2 = (unsigned)__double_as_longlong(k2) & 0xFFFu;
        unsigned i3 = (unsigned)__double_as_longlong(k3) & 0xFFFu;
        float d0 = (float)k0, d1 = (float)k1, d2 = (float)k2, d3 = (float)k3;
        float w0 = __expf(-(d0 + 1e-8f) * 0.5f);
        float w1 = __expf(-(d1 + 1e-8f) * 0.5f);
        float w2 = __expf(-(d2 + 1e-8f) * 0.5f);
        float w3 = __expf(-(d3 + 1e-8f) * 0.5f);
        float inv = 1.0f / (w0 + w1 + w2 + w3 + 1e-8f);
        w0 *= inv; w1 *= inv; w2 *= inv; w3 *= inv;
        float2 g0 = *(const float2*)(xb + ((size_t)i0 << 7) + c);
        float2 g1 = *(const float2*)(xb + ((size_t)i1 << 7) + c);
        float2 g2 = *(const float2*)(xb + ((size_t)i2 << 7) + c);
        float2 g3 = *(const float2*)(xb + ((size_t)i3 << 7) + c);
        float ax = w0 * g0.x + w1 * g1.x + w2 * g2.x + w3 * g3.x;
        float ay = w0 * g0.y + w1 * g1.y + w2 * g2.y + w3 * g3.y;
        sxa[wave][k][c] = ax;
        sxa[wave][k][c + 1] = ay;
    }
    // same-wave LDS RAW: compiler inserts lgkmcnt wait; no barrier needed.

    const unsigned short* wl = sW + (size_t)lane * LSTRIDE;
    float o0x = 0.f, o0y = 0.f, o1x = 0.f, o1y = 0.f;
#pragma unroll 4
    for (int kb = 0; kb < DIM / 8; ++kb) {
        bf16x8 wc0 = *(const bf16x8*)(wl + kb * 8);            // ch c,   k..k+7
        bf16x8 wc1 = *(const bf16x8*)(wl + DIM + kb * 8);      // ch c+1, k..k+7
        f32x4 xr0a = *(const f32x4*)(&sxa[wave][0][kb * 8]);
        f32x4 xr0b = *(const f32x4*)(&sxa[wave][0][kb * 8 + 4]);
        f32x4 xr1a = *(const f32x4*)(&sxa[wave][1][kb * 8]);
        f32x4 xr1b = *(const f32x4*)(&sxa[wave][1][kb * 8 + 4]);
#pragma unroll
        for (int i = 0; i < 4; ++i) {
            float wa = bf2f((unsigned short)wc0[i]);
            float wb = bf2f((unsigned short)wc0[i + 4]);
            float va = bf2f((unsigned short)wc1[i]);
            float vb = bf2f((unsigned short)wc1[i + 4]);
            o0x = fmaf(xr0a[i], wa, o0x); o0x = fmaf(xr0b[i], wb, o0x);
            o0y = fmaf(xr0a[i], va, o0y); o0y = fmaf(xr0b[i], vb, o0y);
            o1x = fmaf(xr1a[i], wa, o1x); o1x = fmaf(xr1b[i], wb, o1x);
            o1y = fmaf(xr1a[i], va, o1y); o1y = fmaf(xr1b[i], vb, o1y);
        }
    }
    float2 bb = *(const float2*)(bias + c);
    *(float2*)(out + (((size_t)(rowbase + wave * 2 + 0)) << 7) + c) =
        make_float2(o0x + bb.x, o0y + bb.y);
    *(float2*)(out + (((size_t)(rowbase + wave * 2 + 1)) << 7) + c) =
        make_float2(o1x + bb.x, o1y + bb.y);
}

extern "C" void kernel_launch(void* const* d_in, const int* in_sizes, int n_in,
                              void* d_out, int out_size, void* d_ws, size_t ws_size,
                              hipStream_t stream) {
    const float* x    = (const float*)d_in[0];  // [2,4096,128]
    const float* pos  = (const float*)d_in[1];  // [2,4096,3]
    const float* W    = (const float*)d_in[2];  // [128,128]
    const float* bias = (const float*)d_in[3];  // [128]
    float* out = (float*)d_out;                 // [2,4096,128] f32

    gnn_fused<<<NROWS / 8, 256, 0, stream>>>(x, pos, W, bias, out);
}

// Round 10
// 88.261 us; speedup vs baseline: 1.0058x; 1.0058x over previous
//
#include <hip/hip_runtime.h>
#include <hip/hip_bf16.h>

#define NPTS 4096
#define NROWS 8192   // B*N
#define DIM 128
#define GEMM_BLOCKS 1024   // 4096 16x16 tiles / 4 waves

typedef __attribute__((ext_vector_type(8))) short bf16x8;
typedef __attribute__((ext_vector_type(4))) float f32x4;

// ---------- K1: fused pos-repack + xW GEMM (R7-verified) ----------
__global__ __launch_bounds__(256) void k1_prep_gemm(const float* __restrict__ x,
                                                    const float* __restrict__ pos,
                                                    const float* __restrict__ W,
                                                    float4* __restrict__ pos4,
                                                    __hip_bfloat16* __restrict__ xWb) {
    int b = blockIdx.x;
    if (b >= GEMM_BLOCKS) {
        int t = (b - GEMM_BLOCKS) * 256 + threadIdx.x;   // 0..8191
        const float* p = pos + (size_t)t * 3;
        pos4[t] = make_float4(p[0], p[1], p[2], 0.f);
        return;
    }
    int wave = threadIdx.x >> 6;
    int lane = threadIdx.x & 63;
    int tile = b * 4 + wave;                   // 0..4095
    int m0 = (tile >> 3) << 4;
    int n0 = (tile & 7) << 4;
    int r = lane & 15;
    int kg = lane >> 4;                        // 0..3
    const float* xr = x + (size_t)(m0 + r) * DIM + kg * 8;
    const float* wc = W + (size_t)(kg * 8) * DIM + (n0 + r);
    f32x4 acc = {0.f, 0.f, 0.f, 0.f};
    union { __hip_bfloat16 h; short s; } u;
#pragma unroll
    for (int kb = 0; kb < 4; ++kb) {
        float4 a0 = *(const float4*)(xr + kb * 32);
        float4 a1 = *(const float4*)(xr + kb * 32 + 4);
        bf16x8 af, bf;
        u.h = __float2bfloat16(a0.x); af[0] = u.s;
        u.h = __float2bfloat16(a0.y); af[1] = u.s;
        u.h = __float2bfloat16(a0.z); af[2] = u.s;
        u.h = __float2bfloat16(a0.w); af[3] = u.s;
        u.h = __float2bfloat16(a1.x); af[4] = u.s;
        u.h = __float2bfloat16(a1.y); af[5] = u.s;
        u.h = __float2bfloat16(a1.z); af[6] = u.s;
        u.h = __float2bfloat16(a1.w); af[7] = u.s;
#pragma unroll
        for (int i = 0; i < 8; ++i) {
            u.h = __float2bfloat16(wc[(size_t)(kb * 32 + i) * DIM]);
            bf[i] = u.s;
        }
        acc = __builtin_amdgcn_mfma_f32_16x16x32_bf16(af, bf, acc, 0, 0, 0);
    }
    int col = n0 + r;
    int rbase = m0 + (kg << 2);
#pragma unroll
    for (int reg = 0; reg < 4; ++reg)
        xWb[(size_t)(rbase + reg) * DIM + col] = __float2bfloat16(acc[reg]);
}

// ---------- exact f64 packed key: key = f64(d2) with low 12 bits = j ----------
__device__ __forceinline__ double mkkey(float d2, int j) {
    return __longlong_as_double(__double_as_longlong((double)d2) |
                                (unsigned long long)(unsigned)j);
}

// sorted-ascending insert: 7 v_min/max_f64
__device__ __forceinline__ void kins(double& k0, double& k1, double& k2,
                                     double& k3, double s) {
    double c = fmax(k0, s); k0 = fmin(k0, s);
    double t = fmax(k1, c); k1 = fmin(k1, c); c = t;
    t = fmax(k2, c);        k2 = fmin(k2, c); c = t;
    k3 = fmin(k3, c);
}

// merge two sorted-asc 4-lists -> 4 smallest sorted: 12 v_min/max_f64
__device__ __forceinline__ void kmerge(double& a0, double& a1, double& a2,
                                       double& a3, double b0, double b1,
                                       double b2, double b3) {
    double m0 = fmin(a0, b3), m1 = fmin(a1, b2);
    double m2 = fmin(a2, b1), m3 = fmin(a3, b0);
    double t0 = fmin(m0, m2), t2 = fmax(m0, m2);
    double t1 = fmin(m1, m3), t3 = fmax(m1, m3);
    a0 = fmin(t0, t1); a1 = fmax(t0, t1);
    a2 = fmin(t2, t3); a3 = fmax(t2, t3);
}

// ---------- K2: R4-chassis topk, 2 candidates per lane-iteration ----------
// 4 waves/block: group = wave>>1 owns rows (2g,2g+1); half = wave&1 scans
// 2048 candidates as 16 iters x 2 points (j, j+64) -> 2x MLP, half the
// loop/addr overhead vs R4's 32x1.
__global__ __launch_bounds__(256) void topk_agg(const float4* __restrict__ pos4,
                                                const __hip_bfloat16* __restrict__ xWb,
                                                const float* __restrict__ bias,
                                                float* __restrict__ out) {
    int lane = threadIdx.x & 63;
    int wave = threadIdx.x >> 6;
    int group = wave >> 1;
    int half = wave & 1;
    int rowbase = blockIdx.x * 4 + group * 2;   // 4 rows/block
    int batch = rowbase >> 12;
    int ibase = rowbase & (NPTS - 1);
    const float4* pb = pos4 + (size_t)batch * NPTS;

    float4 q0 = pb[ibase], q1 = pb[ibase + 1];
    const double INF = __builtin_inf();
    double a0 = INF, a1 = INF, a2 = INF, a3 = INF;   // row 0 keys
    double b0 = INF, b1 = INF, b2 = INF, b3 = INF;   // row 1 keys

    int jbase = (half << 11) + lane;
#pragma unroll 4
    for (int t = 0; t < 16; ++t) {
        int j1 = jbase + (t << 7);
        int j2 = j1 + 64;
        float4 p1 = pb[j1];
        float4 p2 = pb[j2];
        float dx = q0.x - p1.x, dy = q0.y - p1.y, dz = q0.z - p1.z;
        float d2 = fmaf(dx, dx, fmaf(dy, dy, dz * dz));
        kins(a0, a1, a2, a3, mkkey(d2, j1));
        dx = q1.x - p1.x; dy = q1.y - p1.y; dz = q1.z - p1.z;
        d2 = fmaf(dx, dx, fmaf(dy, dy, dz * dz));
        kins(b0, b1, b2, b3, mkkey(d2, j1));
        dx = q0.x - p2.x; dy = q0.y - p2.y; dz = q0.z - p2.z;
        d2 = fmaf(dx, dx, fmaf(dy, dy, dz * dz));
        kins(a0, a1, a2, a3, mkkey(d2, j2));
        dx = q1.x - p2.x; dy = q1.y - p2.y; dz = q1.z - p2.z;
        d2 = fmaf(dx, dx, fmaf(dy, dy, dz * dz));
        kins(b0, b1, b2, b3, mkkey(d2, j2));
    }

    // intra-wave butterfly: 6 xor steps, bitonic merge each
#pragma unroll
    for (int off = 1; off < 64; off <<= 1) {
        double p0 = __shfl_xor(a0, off), p1 = __shfl_xor(a1, off);
        double p2 = __shfl_xor(a2, off), p3 = __shfl_xor(a3, off);
        kmerge(a0, a1, a2, a3, p0, p1, p2, p3);
        p0 = __shfl_xor(b0, off); p1 = __shfl_xor(b1, off);
        p2 = __shfl_xor(b2, off); p3 = __shfl_xor(b3, off);
        kmerge(b0, b1, b2, b3, p0, p1, p2, p3);
    }

    // cross-half exchange via LDS
    __shared__ double lds[2][2][2][4];   // [group][half][row][slot]
    if (lane == 0) {
        lds[group][half][0][0] = a0; lds[group][half][0][1] = a1;
        lds[group][half][0][2] = a2; lds[group][half][0][3] = a3;
        lds[group][half][1][0] = b0; lds[group][half][1][1] = b1;
        lds[group][half][1][2] = b2; lds[group][half][1][3] = b3;
    }
    __syncthreads();
    if (half) return;

    kmerge(a0, a1, a2, a3, lds[group][1][0][0], lds[group][1][0][1],
                           lds[group][1][0][2], lds[group][1][0][3]);
    kmerge(b0, b1, b2, b3, lds[group][1][1][0], lds[group][1][1][1],
                           lds[group][1][1][2], lds[group][1][1][3]);

    // epilogue: lane owns channels (2*lane, 2*lane+1)
    int c = lane << 1;
    float2 bb = *(const float2*)(bias + c);
    const unsigned short* xu = (const unsigned short*)xWb;
    size_t bbase = ((size_t)batch * NPTS) << 7;
#pragma unroll
    for (int k = 0; k < 2; ++k) {
        double k0 = k ? b0 : a0, k1 = k ? b1 : a1;
        double k2 = k ? b2 : a2, k3 = k ? b3 : a3;
        unsigned i0 = (unsigned)__double_as_longlong(k0) & 0xFFFu;
        unsigned i1 = (unsigned)__double_as_longlong(k1) & 0xFFFu;
        unsigned i2 = (unsigned)__double_as_longlong(k2) & 0xFFFu;
        unsigned i3 = (unsigned)__double_as_longlong(k3) & 0xFFFu;
        float d0 = (float)k0, d1 = (float)k1, d2 = (float)k2, d3 = (float)k3;
        float w0 = __expf(-(d0 + 1e-8f) * 0.5f);
        float w1 = __expf(-(d1 + 1e-8f) * 0.5f);
        float w2 = __expf(-(d2 + 1e-8f) * 0.5f);
        float w3 = __expf(-(d3 + 1e-8f) * 0.5f);
        float inv = 1.0f / (w0 + w1 + w2 + w3 + 1e-8f);
        w0 *= inv; w1 *= inv; w2 *= inv; w3 *= inv;
        ushort2 g0 = *(const ushort2*)(xu + bbase + ((size_t)i0 << 7) + c);
        ushort2 g1 = *(const ushort2*)(xu + bbase + ((size_t)i1 << 7) + c);
        ushort2 g2 = *(const ushort2*)(xu + bbase + ((size_t)i2 << 7) + c);
        ushort2 g3 = *(const ushort2*)(xu + bbase + ((size_t)i3 << 7) + c);
        float ox = bb.x + w0 * __uint_as_float((unsigned)g0.x << 16)
                        + w1 * __uint_as_float((unsigned)g1.x << 16)
                        + w2 * __uint_as_float((unsigned)g2.x << 16)
                        + w3 * __uint_as_float((unsigned)g3.x << 16);
        float oy = bb.y + w0 * __uint_as_float((unsigned)g0.y << 16)
                        + w1 * __uint_as_float((unsigned)g1.y << 16)
                        + w2 * __uint_as_float((unsigned)g2.y << 16)
                        + w3 * __uint_as_float((unsigned)g3.y << 16);
        *(float2*)(out + (((size_t)(rowbase + k)) << 7) + c) = make_float2(ox, oy);
    }
}

extern "C" void kernel_launch(void* const* d_in, const int* in_sizes, int n_in,
                              void* d_out, int out_size, void* d_ws, size_t ws_size,
                              hipStream_t stream) {
    const float* x    = (const float*)d_in[0];  // [2,4096,128]
    const float* pos  = (const float*)d_in[1];  // [2,4096,3]
    const float* W    = (const float*)d_in[2];  // [128,128]
    const float* bias = (const float*)d_in[3];  // [128]
    float* out = (float*)d_out;                 // [2,4096,128] f32

    char* ws = (char*)d_ws;
    __hip_bfloat16* xWb = (__hip_bfloat16*)ws;                       // 2 MB
    float4* pos4 = (float4*)(ws + (size_t)NROWS * DIM * 2);          // 128 KB

    k1_prep_gemm<<<GEMM_BLOCKS + NROWS / 256, 256, 0, stream>>>(x, pos, W, pos4, xWb);
    topk_agg<<<NROWS / 4, 256, 0, stream>>>(pos4, xWb, bias, out);
}